// Round 12
// baseline (57.007 us; speedup 1.0000x reference)
//
#include <hip/hip_runtime.h>
#include <stdint.h>

#define NB 4096     // B
#define ND 256      // D

typedef __attribute__((ext_vector_type(8))) short short8;   // 8 bf16 = 4 VGPR
typedef __attribute__((ext_vector_type(4))) float f32x4;

// fp32 -> bf16 RNE
__device__ __forceinline__ unsigned short f2bf(float f) {
    unsigned int u = __float_as_uint(f);
    u += 0x7FFFu + ((u >> 16) & 1u);
    return (unsigned short)(u >> 16);
}

// async global->LDS, 16B per lane. lds dest = wave-uniform base + lane*16.
__device__ __forceinline__ void gload16(const void* g, void* lds_uniform) {
    __builtin_amdgcn_global_load_lds(
        (const __attribute__((address_space(1))) void*)(uintptr_t)g,
        (__attribute__((address_space(3))) void*)(unsigned int)(uintptr_t)lds_uniform,
        16, 0, 0);
}

// ---------------- prep: normalize rows (cos via plain dot), bf16 cast ----------------
__global__ void __launch_bounds__(256) prep_kernel(
    const float* __restrict__ A, const float* __restrict__ Bf,
    unsigned short* __restrict__ Abf, unsigned short* __restrict__ Bbf,
    float* __restrict__ lossws)
{
    if (blockIdx.x == 0 && threadIdx.x < 64) lossws[threadIdx.x << 5] = 0.0f;
    int gw   = (blockIdx.x * 256 + threadIdx.x) >> 6;   // global wave id 0..8191
    int lane = threadIdx.x & 63;
    const float* src; unsigned short* dst; int row;
    if (gw < NB) { src = A;  dst = Abf; row = gw; }
    else         { src = Bf; dst = Bbf; row = gw - NB; }

    float4 v = reinterpret_cast<const float4*>(src + (size_t)row * ND)[lane];
    float ss = v.x * v.x + v.y * v.y + v.z * v.z + v.w * v.w;
    #pragma unroll
    for (int off = 1; off < 64; off <<= 1) ss += __shfl_xor(ss, off);
    float rn = 1.0f / sqrtf(fmaxf(ss, 1e-30f));   // norms ~16, eps never binds

    ushort4 u;
    u.x = f2bf(v.x * rn); u.y = f2bf(v.y * rn);
    u.z = f2bf(v.z * rn); u.w = f2bf(v.w * rn);
    reinterpret_cast<ushort4*>(dst + (size_t)row * ND)[lane] = u;
}

// ---------------- banded GEMM: wave-local staging, no block barriers in K-loop ----------------
// Block (bk,bs) OWNS out rows s in [s0,s0+64), cols k in [k0,k0+128).
// Wave w: k-strip [k0+32w,+32) (A direct global->VGPR), B-window
// [k0+s0+32w, +96) staged wave-locally via global_load_lds (dbuf 2x6KB).
// Per-wave FIFO-counted vmcnt: per iter issue [2 A-loads][6 B-DMA] then
// s_waitcnt vmcnt(8) == "previous stage's 6 DMAs landed" (8 = 2 A + 6 new
// DMAs still outstanding). Compiler's own A-wait is vmcnt(6) (A issued
// BEFORE the new stage) so the prefetch stays in flight. Waves free-run;
// TLP across 12 waves/CU hides the per-wave waits.
__global__ void __launch_bounds__(256, 3) gemm_kernel(
    const unsigned short* __restrict__ Abf, const unsigned short* __restrict__ Bbf,
    const float* __restrict__ labels, float* __restrict__ out,
    float* __restrict__ lossws)
{
    // staging: wave w owns [w*12288, +12288) = dbuf 2 x 6144
    // epilogue (after sync): dw [0,32768) 64x128 f32; lpart [49152,49168)
    __shared__ __align__(16) char smem[49168];

    const int tid = threadIdx.x;
    const int w = tid >> 6, lane = tid & 63;
    const int lane15 = lane & 15, lhi = lane >> 4;

    // XCD-chunked order, bs-fast (consecutive blocks share the A panel)
    const int bid = ((blockIdx.x & 7) << 8) + (blockIdx.x >> 3);
    const int bk = bid >> 6, bs = bid & 63;
    const int k0 = bk << 7, s0 = bs << 6;
    const int kw = k0 + (w << 5);
    const int jw = (kw + s0) & (NB - 1);      // wave's B-window start

    char* wbase = smem + w * 12288;

    // A: direct per-lane fragment pointers (16 rows x 64B lines per load)
    const short8* aptr0 = reinterpret_cast<const short8*>(Abf + (size_t)(kw + lane15) * ND) + lhi;
    const short8* aptr1 = reinterpret_cast<const short8*>(Abf + (size_t)(kw + 16 + lane15) * ND) + lhi;

    // B staging sources (per-lane, loop-invariant); +kt*64B folds to imm.
    // physical chunk pc at row holds logical chunk pc ^ f(row), f=(row^(row>>2))&3
    const unsigned short* bsrc[6];
    #pragma unroll
    for (int i = 0; i < 6; ++i) {
        int slot = (i << 6) + lane;
        int row  = slot >> 2;                 // 0..95 within wave window
        int srow = (jw + row) & (NB - 1);
        int sch  = (slot ^ (slot >> 2) ^ (slot >> 4)) & 3;
        bsrc[i]  = Bbf + (size_t)srow * ND + (sch << 3);
    }

    auto stageB = [&](int kt) {
        char* buf = wbase + ((kt & 1) ? 6144 : 0);
        #pragma unroll
        for (int i = 0; i < 6; ++i)
            gload16(bsrc[i] + (kt << 5), buf + (i << 10));
    };

    f32x4 acc[2][5];
    #pragma unroll
    for (int m = 0; m < 2; ++m)
        #pragma unroll
        for (int r = 0; r < 5; ++r) acc[m][r] = (f32x4)0.0f;

    stageB(0);                                 // S_0 in flight (6)

    #pragma unroll
    for (int kt = 0; kt < 8; ++kt) {          // K = 256 in 8 chunks of BK=32
        // issue order matters for FIFO counting: A first, then next stage
        short8 a0 = aptr0[kt << 2];            // +2 vmcnt
        short8 a1 = aptr1[kt << 2];
        if (kt < 7) stageB(kt + 1);            // +6 vmcnt (stays in flight)

        __builtin_amdgcn_sched_barrier(0);     // pin issues above the wait
        if (kt < 7) asm volatile("s_waitcnt vmcnt(8)");  // S_kt landed; A_kt+S_{kt+1} in flight
        else        asm volatile("s_waitcnt vmcnt(2)");  // S_7 landed; A_7 in flight
        __builtin_amdgcn_sched_barrier(0);     // pin ds_reads below the wait

        char* buf = wbase + ((kt & 1) ? 6144 : 0);
        const int f = (lane15 ^ (lane15 >> 2)) & 3;   // = f(row) for rows below
        short8 b[6];
        #pragma unroll
        for (int jf = 0; jf < 6; ++jf) {
            int row = (jf << 4) + lane15;
            b[jf] = *reinterpret_cast<const short8*>(buf + row * 64 + ((lhi ^ f) << 4));
        }
        #pragma unroll
        for (int r = 0; r < 5; ++r)
            acc[0][r] = __builtin_amdgcn_mfma_f32_16x16x32_bf16(a0, b[r], acc[0][r], 0, 0, 0);
        #pragma unroll
        for (int r = 0; r < 5; ++r)
            acc[1][r] = __builtin_amdgcn_mfma_f32_16x16x32_bf16(a1, b[1 + r], acc[1][r], 0, 0, 0);

        // end-of-iter fence: next iter's stage (writes buf of parity kt+1 == kt-1)
        // must not hoist above this iter's ds_reads (WAR on the double buffer)
        __builtin_amdgcn_sched_barrier(0);
    }

    __syncthreads();   // all waves done; dw may overwrite staging regions

    // ---- scatter: (t, kap) -> dw[t][kap ^ (t&31)]  (measured ~free banks) ----
    // t = s-local = 16r + lane15 - 4lhi - e in [0,64); kap = block-local k col
    float* dw    = reinterpret_cast<float*>(smem);          // 64 x 128 f32
    float* lpart = reinterpret_cast<float*>(smem + 49152);  // 4 f32
    #pragma unroll
    for (int m = 0; m < 2; ++m)
        #pragma unroll
        for (int r = 0; r < 5; ++r)
            #pragma unroll
            for (int e = 0; e < 4; ++e) {
                int t = (r << 4) + lane15 - (lhi << 2) - e;
                if ((unsigned)t < 64u) {
                    int kap = (w << 5) + (m << 4) + (lhi << 2) + e;
                    dw[(t << 7) + (kap ^ (t & 31))] = acc[m][r][e];
                }
            }
    __syncthreads();

    // ---- gather rows (strided ownership t = w + 4*lane15), store + loss ----
    const int t = w + (lane15 << 2);
    const int s = s0 + t;
    const int x3 = w & 3;                      // wave-uniform within-quad perm
    const float* rowp = dw + (t << 7);
    float lacc = 0.0f;

    #pragma unroll
    for (int i = 0; i < 8; ++i) {
        int qlog  = lhi + (i << 2);            // logical quad 0..31
        int physq = qlog ^ (lane15 & 7);       // 8 distinct bank-quads per instr
        f32x4 d = *reinterpret_cast<const f32x4*>(rowp + (physq << 2));
        f32x4 v;
        if      (x3 == 0) { v = d; }
        else if (x3 == 1) { v[0] = d[1]; v[1] = d[0]; v[2] = d[3]; v[3] = d[2]; }
        else if (x3 == 2) { v[0] = d[2]; v[1] = d[3]; v[2] = d[0]; v[3] = d[1]; }
        else              { v[0] = d[3]; v[1] = d[2]; v[2] = d[1]; v[3] = d[0]; }

        f32x4 x, y;
        #pragma unroll
        for (int e = 0; e < 4; ++e) {
            x[e] = fmaf(v[e],  0.5f, 0.5f);    // logit
            y[e] = fmaf(v[e], -0.5f, 0.5f);    // 1 - logit (exact)
        }
        *reinterpret_cast<f32x4*>(out + (size_t)s * NB + k0 + (qlog << 2)) = x;

        float l1p0 = fmaxf(__logf(y[0]), -100.0f);
        float l1p1 = fmaxf(__logf(y[1]), -100.0f);
        float l1p2 = fmaxf(__logf(y[2]), -100.0f);
        float l1p3 = fmaxf(__logf(y[3]), -100.0f);
        if (s == 0) {   // weight-1 labeled row
            float l1pv[4] = {l1p0, l1p1, l1p2, l1p3};
            #pragma unroll
            for (int e = 0; e < 4; ++e) {
                float lab = labels[k0 + (qlog << 2) + e];
                float lp  = fmaxf(__logf(x[e]), -100.0f);
                lacc += lab * lp + (1.0f - lab) * l1pv[e];
            }
        } else {
            lacc += 0.5f * (l1p0 + l1p1 + l1p2 + l1p3);   // NEG_WEIGHT
        }
    }

    #pragma unroll
    for (int off = 32; off > 0; off >>= 1) lacc += __shfl_down(lacc, off);
    if (lane == 0) lpart[w] = lacc;
    __syncthreads();
    if (tid == 0) {
        float tot = lpart[0] + lpart[1] + lpart[2] + lpart[3];
        atomicAdd(lossws + ((bid & 63) << 5), -tot);
    }
}

__global__ void finalize_kernel(const float* __restrict__ lossws, float* __restrict__ out) {
    float s = 0.0f;
    for (int i = 0; i < 64; ++i) s += lossws[i << 5];
    out[(size_t)NB * NB] = s;
}

extern "C" void kernel_launch(void* const* d_in, const int* in_sizes, int n_in,
                              void* d_out, int out_size, void* d_ws, size_t ws_size,
                              hipStream_t stream) {
    (void)in_sizes; (void)n_in; (void)out_size; (void)ws_size;
    const float* A      = (const float*)d_in[0];
    const float* Bf     = (const float*)d_in[1];
    const float* labels = (const float*)d_in[2];
    float* out = (float*)d_out;

    char* ws = (char*)d_ws;
    unsigned short* Abf = (unsigned short*)ws;                                  // 2 MB
    unsigned short* Bbf = (unsigned short*)(ws + (size_t)2 * 1024 * 1024);      // 2 MB
    float* lossws = (float*)(ws + (size_t)4 * 1024 * 1024);                     // 8 KB (64 cells x 128B)

    hipLaunchKernelGGL(prep_kernel, dim3(2048), dim3(256), 0, stream,
                       A, Bf, Abf, Bbf, lossws);
    hipLaunchKernelGGL(gemm_kernel, dim3(2048), dim3(256), 0, stream,
                       Abf, Bbf, labels, out, lossws);
    hipLaunchKernelGGL(finalize_kernel, dim3(1), dim3(1), 0, stream, lossws, out);
}

// Round 13
// 50.181 us; speedup vs baseline: 1.1360x; 1.1360x over previous
//
#include <hip/hip_runtime.h>
#include <stdint.h>

#define NB 4096     // B
#define ND 256      // D

typedef __attribute__((ext_vector_type(8))) short short8;   // 8 bf16 = 4 VGPR
typedef __attribute__((ext_vector_type(4))) float f32x4;

// fp32 -> bf16 RNE
__device__ __forceinline__ unsigned short f2bf(float f) {
    unsigned int u = __float_as_uint(f);
    u += 0x7FFFu + ((u >> 16) & 1u);
    return (unsigned short)(u >> 16);
}

// async global->LDS, 16B per lane. lds dest = wave-uniform base + lane*16.
__device__ __forceinline__ void gload16(const void* g, void* lds_uniform) {
    __builtin_amdgcn_global_load_lds(
        (const __attribute__((address_space(1))) void*)(uintptr_t)g,
        (__attribute__((address_space(3))) void*)(unsigned int)(uintptr_t)lds_uniform,
        16, 0, 0);
}

// ---------------- prep: normalize rows (cos via plain dot), bf16 cast ----------------
__global__ void __launch_bounds__(256) prep_kernel(
    const float* __restrict__ A, const float* __restrict__ Bf,
    unsigned short* __restrict__ Abf, unsigned short* __restrict__ Bbf,
    float* __restrict__ lossws)
{
    if (blockIdx.x == 0 && threadIdx.x < 64) lossws[threadIdx.x << 5] = 0.0f;
    int gw   = (blockIdx.x * 256 + threadIdx.x) >> 6;   // global wave id 0..8191
    int lane = threadIdx.x & 63;
    const float* src; unsigned short* dst; int row;
    if (gw < NB) { src = A;  dst = Abf; row = gw; }
    else         { src = Bf; dst = Bbf; row = gw - NB; }

    float4 v = reinterpret_cast<const float4*>(src + (size_t)row * ND)[lane];
    float ss = v.x * v.x + v.y * v.y + v.z * v.z + v.w * v.w;
    #pragma unroll
    for (int off = 1; off < 64; off <<= 1) ss += __shfl_xor(ss, off);
    float rn = 1.0f / sqrtf(fmaxf(ss, 1e-30f));   // norms ~16, eps never binds

    ushort4 u;
    u.x = f2bf(v.x * rn); u.y = f2bf(v.y * rn);
    u.z = f2bf(v.z * rn); u.w = f2bf(v.w * rn);
    reinterpret_cast<ushort4*>(dst + (size_t)row * ND)[lane] = u;
}

// ---------------- fused banded GEMM + row-owned epilogue + BCE loss ----------------
// Block (bk,bs) OWNS out rows s in [s0,s0+128), cols k in [k0,k0+128).
// Band: B-rows j in [k0+s0, k0+s0+256), staged once per block.
// 4 waves in 2x2 (kw,sw): wave = k-strip [64kw,+64) x s-half [64sw,+64):
// 4 A-frags + 8 B-frags -> 20 MFMA per K=32 step (0.6 KB LDS per MFMA).
// BK=32 double-buffered staging (2 x 24KB), 2-phase lockstep (proven best).
__global__ void __launch_bounds__(256, 3) gemm_kernel(
    const unsigned short* __restrict__ Abf, const unsigned short* __restrict__ Bbf,
    const float* __restrict__ labels, float* __restrict__ out,
    float* __restrict__ lossws)
{
    // buf0 [0,24576): A 8K | B 16K ; buf1 [24576,49152)
    // epilogue: dw [0,32768) (64 x 128 f32) x 2 passes; lpart [49152,49168)
    __shared__ __align__(16) char smem[49168];

    const int tid = threadIdx.x;
    const int w = tid >> 6, lane = tid & 63;
    const int lane15 = lane & 15, lhi = lane >> 4;
    const int kw_ = w >> 1, sw_ = w & 1;       // 2x2 wave grid
    const int bid = blockIdx.x;
    const int bk = bid >> 5, bs = bid & 31;
    const int k0 = bk << 7, s0 = bs << 7;
    const int j0 = (k0 + s0) & (NB - 1);

    f32x4 acc[4][5];
    #pragma unroll
    for (int mk = 0; mk < 4; ++mk)
        #pragma unroll
        for (int r = 0; r < 5; ++r) acc[mk][r] = (f32x4)0.0f;

    // staging sources (per-lane, loop-invariant); +kt*64B folds to imm.
    // physical chunk pc at row holds logical chunk pc ^ f(row), f=(row^(row>>2))&3
    const unsigned short* asrc[2];
    const unsigned short* bsrc[4];
    int aslot0[2], bslot0[4];
    #pragma unroll
    for (int i = 0; i < 2; ++i) {              // A: 128 rows -> 512 slots
        int slot0 = (i << 8) + (w << 6);
        int slot  = slot0 + lane;
        int sch   = (slot ^ (slot >> 2) ^ (slot >> 4)) & 3;
        asrc[i]   = Abf + (size_t)(k0 + (slot >> 2)) * ND + (sch << 3);
        aslot0[i] = slot0;
    }
    #pragma unroll
    for (int i = 0; i < 4; ++i) {              // B: 256 rows -> 1024 slots
        int slot0 = (i << 8) + (w << 6);
        int slot  = slot0 + lane;
        int srow  = (j0 + (slot >> 2)) & (NB - 1);
        int sch   = (slot ^ (slot >> 2) ^ (slot >> 4)) & 3;
        bsrc[i]   = Bbf + (size_t)srow * ND + (sch << 3);
        bslot0[i] = slot0;
    }

    auto stage = [&](int kt, char* buf) {
        #pragma unroll
        for (int i = 0; i < 2; ++i)
            gload16(asrc[i] + (kt << 5), buf + aslot0[i] * 16);
        #pragma unroll
        for (int i = 0; i < 4; ++i)
            gload16(bsrc[i] + (kt << 5), buf + 8192 + bslot0[i] * 16);
    };

    stage(0, smem);
    __syncthreads();   // buf0 ready

    #pragma unroll
    for (int kt = 0; kt < 8; ++kt) {           // K = 256 in 8 chunks of BK=32
        char* buf = smem + ((kt & 1) ? 24576 : 0);
        if (kt < 7) stage(kt + 1, smem + ((kt & 1) ? 0 : 24576));  // issue-early prefetch

        const int f = (lane15 ^ (lane15 >> 2)) & 3;   // = f(row) for rows read below
        short8 a[4], b[8];
        #pragma unroll
        for (int mk = 0; mk < 4; ++mk) {
            int row = (kw_ << 6) + (mk << 4) + lane15;
            a[mk] = *reinterpret_cast<const short8*>(buf + row * 64 + ((lhi ^ f) << 4));
        }
        #pragma unroll
        for (int q = 0; q < 8; ++q) {
            int row = ((kw_ + sw_) << 6) + (q << 4) + lane15;   // block j-frag 4(kw+sw)+q
            b[q] = *reinterpret_cast<const short8*>(buf + 8192 + row * 64 + ((lhi ^ f) << 4));
        }
        #pragma unroll
        for (int mk = 0; mk < 4; ++mk)
            #pragma unroll
            for (int r = 0; r < 5; ++r)
                acc[mk][r] = __builtin_amdgcn_mfma_f32_16x16x32_bf16(
                    a[mk], b[mk + r], acc[mk][r], 0, 0, 0);
        __syncthreads();   // reads done; prefetched buffer landed
    }

    // ---- epilogue: two 64-row passes through dw[64][128] ----
    // element (mk,r,e): t = 16r+lane15-4lhi-e in [0,64); s_local = 64*sw_ + t;
    // kap = 64*kw_ + 16mk + 4lhi + e. Pass p handles s_local in [64p, 64p+64):
    // waves with sw_==p scatter (disjoint kap halves), all waves gather.
    float* dw    = reinterpret_cast<float*>(smem);          // 64 x 128 f32
    float* lpart = reinterpret_cast<float*>(smem + 49152);  // 4 f32
    float lacc = 0.0f;

    #pragma unroll
    for (int p = 0; p < 2; ++p) {
        if (sw_ == p) {
            #pragma unroll
            for (int mk = 0; mk < 4; ++mk)
                #pragma unroll
                for (int r = 0; r < 5; ++r)
                    #pragma unroll
                    for (int e = 0; e < 4; ++e) {
                        int t = (r << 4) + lane15 - (lhi << 2) - e;
                        if ((unsigned)t < 64u) {
                            int kap = (kw_ << 6) + (mk << 4) + (lhi << 2) + e;
                            dw[(t << 7) + (kap ^ (t & 31))] = acc[mk][r][e];
                        }
                    }
        }
        __syncthreads();

        // gather rows (strided ownership t = w + 4*lane15), store + loss
        const int t = w + (lane15 << 2);
        const int s = s0 + (p << 6) + t;
        const int x3 = w & 3;                  // wave-uniform within-quad perm
        const float* rowp = dw + (t << 7);

        #pragma unroll
        for (int i = 0; i < 8; ++i) {
            int qlog  = lhi + (i << 2);        // logical quad 0..31
            int physq = qlog ^ (lane15 & 7);   // 8 distinct bank-quads per instr
            f32x4 d = *reinterpret_cast<const f32x4*>(rowp + (physq << 2));
            f32x4 v;
            if      (x3 == 0) { v = d; }
            else if (x3 == 1) { v[0] = d[1]; v[1] = d[0]; v[2] = d[3]; v[3] = d[2]; }
            else if (x3 == 2) { v[0] = d[2]; v[1] = d[3]; v[2] = d[0]; v[3] = d[1]; }
            else              { v[0] = d[3]; v[1] = d[2]; v[2] = d[1]; v[3] = d[0]; }

            f32x4 x, y;
            #pragma unroll
            for (int e = 0; e < 4; ++e) {
                x[e] = fmaf(v[e],  0.5f, 0.5f);    // logit
                y[e] = fmaf(v[e], -0.5f, 0.5f);    // 1 - logit (exact)
            }
            *reinterpret_cast<f32x4*>(out + (size_t)s * NB + k0 + (qlog << 2)) = x;

            float l1p0 = fmaxf(__logf(y[0]), -100.0f);
            float l1p1 = fmaxf(__logf(y[1]), -100.0f);
            float l1p2 = fmaxf(__logf(y[2]), -100.0f);
            float l1p3 = fmaxf(__logf(y[3]), -100.0f);
            if (s == 0) {   // weight-1 labeled row
                float l1pv[4] = {l1p0, l1p1, l1p2, l1p3};
                #pragma unroll
                for (int e = 0; e < 4; ++e) {
                    float lab = labels[k0 + (qlog << 2) + e];
                    float lp  = fmaxf(__logf(x[e]), -100.0f);
                    lacc += lab * lp + (1.0f - lab) * l1pv[e];
                }
            } else {
                lacc += 0.5f * (l1p0 + l1p1 + l1p2 + l1p3);   // NEG_WEIGHT
            }
        }
        __syncthreads();   // dw reusable for next pass
    }

    #pragma unroll
    for (int off = 32; off > 0; off >>= 1) lacc += __shfl_down(lacc, off);
    if (lane == 0) lpart[w] = lacc;
    __syncthreads();
    if (tid == 0) {
        float tot = lpart[0] + lpart[1] + lpart[2] + lpart[3];
        atomicAdd(lossws + ((bid & 63) << 5), -tot);
    }
}

__global__ void finalize_kernel(const float* __restrict__ lossws, float* __restrict__ out) {
    float s = 0.0f;
    for (int i = 0; i < 64; ++i) s += lossws[i << 5];
    out[(size_t)NB * NB] = s;
}

extern "C" void kernel_launch(void* const* d_in, const int* in_sizes, int n_in,
                              void* d_out, int out_size, void* d_ws, size_t ws_size,
                              hipStream_t stream) {
    (void)in_sizes; (void)n_in; (void)out_size; (void)ws_size;
    const float* A      = (const float*)d_in[0];
    const float* Bf     = (const float*)d_in[1];
    const float* labels = (const float*)d_in[2];
    float* out = (float*)d_out;

    char* ws = (char*)d_ws;
    unsigned short* Abf = (unsigned short*)ws;                                  // 2 MB
    unsigned short* Bbf = (unsigned short*)(ws + (size_t)2 * 1024 * 1024);      // 2 MB
    float* lossws = (float*)(ws + (size_t)4 * 1024 * 1024);                     // 8 KB (64 cells x 128B)

    hipLaunchKernelGGL(prep_kernel, dim3(2048), dim3(256), 0, stream,
                       A, Bf, Abf, Bbf, lossws);
    hipLaunchKernelGGL(gemm_kernel, dim3(1024), dim3(256), 0, stream,
                       Abf, Bbf, labels, out, lossws);
    hipLaunchKernelGGL(finalize_kernel, dim3(1), dim3(1), 0, stream, lossws, out);
}